// Round 1
// baseline (2876.576 us; speedup 1.0000x reference)
//
#include <hip/hip_runtime.h>

#define N_NODES 100000
#define N_EDGES 1600000
#define D 64

// ---------------- degree ----------------
__global__ void init_deg(float* __restrict__ deg, int n) {
    int i = blockIdx.x * blockDim.x + threadIdx.x;
    if (i < n) deg[i] = 1.0f;  // self-loop
}

__global__ void count_deg(const int* __restrict__ dst, float* __restrict__ deg, int ne) {
    int i = blockIdx.x * blockDim.x + threadIdx.x;
    if (i < ne) unsafeAtomicAdd(&deg[dst[i]], 1.0f);
}

__global__ void compute_dinv(const float* __restrict__ deg, float* __restrict__ dinv, int n) {
    int i = blockIdx.x * blockDim.x + threadIdx.x;
    if (i < n) dinv[i] = rsqrtf(deg[i]);
}

// ---------------- h = x @ W  (x: [n,64], W: [64,64] row-major) ----------------
// 256 threads = 4 rows x 64 cols per iteration. W column held in registers
// (64 VGPR), x rows broadcast via LDS.
__global__ void linear64(const float* __restrict__ x, const float* __restrict__ W,
                         float* __restrict__ y, int nrows) {
    __shared__ float xs[4][64];
    const int col = threadIdx.x & 63;
    const int rl  = threadIdx.x >> 6;  // 0..3

    float wcol[64];
#pragma unroll
    for (int k = 0; k < 64; ++k) wcol[k] = W[k * 64 + col];

    for (int r0 = blockIdx.x * 4; r0 < nrows; r0 += gridDim.x * 4) {
        const int row = r0 + rl;  // nrows % 4 == 0, always valid
        xs[rl][col] = x[(size_t)row * 64 + col];
        __syncthreads();
        float acc = 0.0f;
#pragma unroll
        for (int k = 0; k < 64; ++k) acc = fmaf(xs[rl][k], wcol[k], acc);
        y[(size_t)row * 64 + col] = acc;
        __syncthreads();
    }
}

// ---------------- zero ----------------
__global__ void zero_buf(float4* __restrict__ p, int n4) {
    int i = blockIdx.x * blockDim.x + threadIdx.x;
    if (i < n4) p[i] = make_float4(0.f, 0.f, 0.f, 0.f);
}

// ---------------- edge scatter: agg[dst] += h[src] * dinv[src]*dinv[dst] ----------------
// 16 lanes per edge, float4 per lane.
__global__ void scatter_edges(const float* __restrict__ h, const int* __restrict__ src,
                              const int* __restrict__ dst, const float* __restrict__ dinv,
                              float* __restrict__ agg, int ne) {
    int g = blockIdx.x * blockDim.x + threadIdx.x;
    int e = g >> 4;
    int lane = g & 15;
    if (e >= ne) return;
    const int s = src[e];
    const int d = dst[e];
    const float norm = dinv[s] * dinv[d];
    const float4 v = reinterpret_cast<const float4*>(h + (size_t)s * D)[lane];
    float* o = agg + (size_t)d * D + lane * 4;
    unsafeAtomicAdd(o + 0, v.x * norm);
    unsafeAtomicAdd(o + 1, v.y * norm);
    unsafeAtomicAdd(o + 2, v.z * norm);
    unsafeAtomicAdd(o + 3, v.w * norm);
}

// ---------------- out = relu(agg + h * (1/deg) + b) ----------------
__global__ void finalize(const float4* __restrict__ agg, const float4* __restrict__ h,
                         const float* __restrict__ dinv, const float* __restrict__ bias,
                         float4* __restrict__ out, int n4) {
    int i = blockIdx.x * blockDim.x + threadIdx.x;
    if (i >= n4) return;
    const int node = i >> 4;
    const int j4 = i & 15;
    const float dv = dinv[node];
    const float selfc = dv * dv;  // 1/deg
    const float4 bv = reinterpret_cast<const float4*>(bias)[j4];
    const float4 a = agg[i];
    const float4 hh = h[i];
    float4 r;
    r.x = fmaxf(fmaf(hh.x, selfc, a.x) + bv.x, 0.f);
    r.y = fmaxf(fmaf(hh.y, selfc, a.y) + bv.y, 0.f);
    r.z = fmaxf(fmaf(hh.z, selfc, a.z) + bv.z, 0.f);
    r.w = fmaxf(fmaf(hh.w, selfc, a.w) + bv.w, 0.f);
    out[i] = r;
}

extern "C" void kernel_launch(void* const* d_in, const int* in_sizes, int n_in,
                              void* d_out, int out_size, void* d_ws, size_t ws_size,
                              hipStream_t stream) {
    const float* feature = (const float*)d_in[0];
    const int*   edges   = (const int*)d_in[1];   // [2, E] flat: src then dst
    const float* W1      = (const float*)d_in[2];
    const float* b1      = (const float*)d_in[3];
    const float* W2      = (const float*)d_in[4];
    const float* b2      = (const float*)d_in[5];
    float* out = (float*)d_out;

    const int* src = edges;
    const int* dst = edges + N_EDGES;

    float* deg  = (float*)d_ws;                 // N
    float* dinv = deg + N_NODES;                // N
    float* h    = dinv + N_NODES;               // N*D
    float* agg  = h + (size_t)N_NODES * D;      // N*D

    const int nd4 = N_NODES * (D / 4);          // 1.6M float4s

    // degrees (shared by both layers)
    init_deg<<<(N_NODES + 255) / 256, 256, 0, stream>>>(deg, N_NODES);
    count_deg<<<(N_EDGES + 255) / 256, 256, 0, stream>>>(dst, deg, N_EDGES);
    compute_dinv<<<(N_NODES + 255) / 256, 256, 0, stream>>>(deg, dinv, N_NODES);

    const int scatter_blocks = (N_EDGES * 16 + 255) / 256;

    // ---- layer 1 ----
    linear64<<<2048, 256, 0, stream>>>(feature, W1, h, N_NODES);
    zero_buf<<<(nd4 + 255) / 256, 256, 0, stream>>>((float4*)agg, nd4);
    scatter_edges<<<scatter_blocks, 256, 0, stream>>>(h, src, dst, dinv, agg, N_EDGES);
    // y1 = relu(...) -> reuse d_out as the layer-1 activation buffer
    finalize<<<(nd4 + 255) / 256, 256, 0, stream>>>((const float4*)agg, (const float4*)h,
                                                    dinv, b1, (float4*)out, nd4);

    // ---- layer 2 ----
    linear64<<<2048, 256, 0, stream>>>(out, W2, h, N_NODES);
    zero_buf<<<(nd4 + 255) / 256, 256, 0, stream>>>((float4*)agg, nd4);
    scatter_edges<<<scatter_blocks, 256, 0, stream>>>(h, src, dst, dinv, agg, N_EDGES);
    finalize<<<(nd4 + 255) / 256, 256, 0, stream>>>((const float4*)agg, (const float4*)h,
                                                    dinv, b2, (float4*)out, nd4);
}

// Round 2
// 485.321 us; speedup vs baseline: 5.9272x; 5.9272x over previous
//
#include <hip/hip_runtime.h>

#define N_NODES 100000
#define N_EDGES 1600000
#define D 64
#define SCAN_B 256

// ---------------- zero int buffer ----------------
__global__ void zero_int(int* __restrict__ p, int n) {
    int i = blockIdx.x * blockDim.x + threadIdx.x;
    if (i < n) p[i] = 0;
}

// ---------------- histogram of dst ----------------
__global__ void count_deg(const int* __restrict__ dst, int* __restrict__ cnt, int ne) {
    int i = blockIdx.x * blockDim.x + threadIdx.x;
    if (i < ne) atomicAdd(&cnt[dst[i]], 1);
}

// ---------------- dinv = rsqrt(cnt + 1)  (self-loop) ----------------
__global__ void compute_dinv(const int* __restrict__ cnt, float* __restrict__ dinv, int n) {
    int i = blockIdx.x * blockDim.x + threadIdx.x;
    if (i < n) dinv[i] = rsqrtf((float)cnt[i] + 1.0f);
}

// ---------------- exclusive prefix scan of cnt -> rowptr (3 phases) ----------------
__global__ void scan_block_sums(const int* __restrict__ cnt, int* __restrict__ bsum, int n) {
    __shared__ int s[SCAN_B];
    int i = blockIdx.x * SCAN_B + threadIdx.x;
    s[threadIdx.x] = (i < n) ? cnt[i] : 0;
    __syncthreads();
    for (int off = SCAN_B / 2; off > 0; off >>= 1) {
        if (threadIdx.x < off) s[threadIdx.x] += s[threadIdx.x + off];
        __syncthreads();
    }
    if (threadIdx.x == 0) bsum[blockIdx.x] = s[0];
}

__global__ void scan_bsums(int* __restrict__ bsum, int nb, int* __restrict__ rowptr, int n) {
    if (blockIdx.x == 0 && threadIdx.x == 0) {
        int acc = 0;
        for (int i = 0; i < nb; ++i) { int t = bsum[i]; bsum[i] = acc; acc += t; }
        rowptr[n] = acc;  // total = N_EDGES
    }
}

__global__ void scan_final(const int* __restrict__ cnt, const int* __restrict__ bsum,
                           int* __restrict__ rowptr, int* __restrict__ cursor, int n) {
    __shared__ int s[SCAN_B];
    int i = blockIdx.x * SCAN_B + threadIdx.x;
    int v = (i < n) ? cnt[i] : 0;
    s[threadIdx.x] = v;
    __syncthreads();
    for (int off = 1; off < SCAN_B; off <<= 1) {
        int t = (threadIdx.x >= off) ? s[threadIdx.x - off] : 0;
        __syncthreads();
        s[threadIdx.x] += t;
        __syncthreads();
    }
    if (i < n) {
        int excl = s[threadIdx.x] - v + bsum[blockIdx.x];
        rowptr[i] = excl;
        cursor[i] = excl;
    }
}

// ---------------- bucket edges: col[pos]=src, enorm[pos]=dinv[s]*dinv[d] ----------------
__global__ void build_csr(const int* __restrict__ src, const int* __restrict__ dst,
                          const float* __restrict__ dinv, int* __restrict__ cursor,
                          int* __restrict__ col, float* __restrict__ enorm, int ne) {
    int e = blockIdx.x * blockDim.x + threadIdx.x;
    if (e >= ne) return;
    int s = src[e], d = dst[e];
    int pos = atomicAdd(&cursor[d], 1);
    col[pos] = s;
    enorm[pos] = dinv[s] * dinv[d];
}

// ---------------- h = x @ W  (x: [n,64], W: [64,64] row-major) ----------------
__global__ void linear64(const float* __restrict__ x, const float* __restrict__ W,
                         float* __restrict__ y, int nrows) {
    __shared__ float xs[4][64];
    const int col = threadIdx.x & 63;
    const int rl  = threadIdx.x >> 6;  // 0..3

    float wcol[64];
#pragma unroll
    for (int k = 0; k < 64; ++k) wcol[k] = W[k * 64 + col];

    for (int r0 = blockIdx.x * 4; r0 < nrows; r0 += gridDim.x * 4) {
        const int row = r0 + rl;  // nrows % 4 == 0
        xs[rl][col] = x[(size_t)row * 64 + col];
        __syncthreads();
        float acc = 0.0f;
#pragma unroll
        for (int k = 0; k < 64; ++k) acc = fmaf(xs[rl][k], wcol[k], acc);
        y[(size_t)row * 64 + col] = acc;
        __syncthreads();
    }
}

// ---------------- aggregate + self-loop + bias + relu, one wave per node ----------------
__global__ __launch_bounds__(256) void aggregate(
        const float* __restrict__ h, const int* __restrict__ rowptr,
        const int* __restrict__ col, const float* __restrict__ enorm,
        const float* __restrict__ dinv, const float* __restrict__ bias,
        float* __restrict__ out, int n) {
    const int node = blockIdx.x * 4 + (threadIdx.x >> 6);
    const int lane = threadIdx.x & 63;
    if (node >= n) return;
    const int beg = rowptr[node];
    const int end = rowptr[node + 1];

    float acc0 = 0.f, acc1 = 0.f;
    int j = beg;
    for (; j + 1 < end; j += 2) {
        const int s0 = col[j], s1 = col[j + 1];
        const float n0 = enorm[j], n1 = enorm[j + 1];
        acc0 = fmaf(h[(size_t)s0 * D + lane], n0, acc0);
        acc1 = fmaf(h[(size_t)s1 * D + lane], n1, acc1);
    }
    if (j < end) acc0 = fmaf(h[(size_t)col[j] * D + lane], enorm[j], acc0);

    const float dv = dinv[node];
    float acc = acc0 + acc1;
    acc = fmaf(h[(size_t)node * D + lane], dv * dv, acc);  // self loop (1/deg)
    acc += bias[lane];
    out[(size_t)node * D + lane] = fmaxf(acc, 0.f);
}

extern "C" void kernel_launch(void* const* d_in, const int* in_sizes, int n_in,
                              void* d_out, int out_size, void* d_ws, size_t ws_size,
                              hipStream_t stream) {
    const float* feature = (const float*)d_in[0];
    const int*   edges   = (const int*)d_in[1];   // [2, E] flat: src then dst
    const float* W1      = (const float*)d_in[2];
    const float* b1      = (const float*)d_in[3];
    const float* W2      = (const float*)d_in[4];
    const float* b2      = (const float*)d_in[5];
    float* out = (float*)d_out;

    const int* src = edges;
    const int* dst = edges + N_EDGES;

    // workspace layout
    char* w = (char*)d_ws;
    int*   cnt    = (int*)w;            w += sizeof(int) * (N_NODES);
    int*   rowptr = (int*)w;            w += sizeof(int) * (N_NODES + 1);
    int*   cursor = (int*)w;            w += sizeof(int) * (N_NODES);
    int*   bsum   = (int*)w;            w += sizeof(int) * ((N_NODES + SCAN_B - 1) / SCAN_B + 1);
    int*   colA   = (int*)w;            w += sizeof(int) * (N_EDGES);
    float* enorm  = (float*)w;          w += sizeof(float) * (N_EDGES);
    float* dinv   = (float*)w;          w += sizeof(float) * (N_NODES);
    float* h      = (float*)w;          w += sizeof(float) * ((size_t)N_NODES * D);

    const int nb = (N_NODES + SCAN_B - 1) / SCAN_B;

    // ---- CSR build (once, shared by both layers) ----
    zero_int<<<(N_NODES + 255) / 256, 256, 0, stream>>>(cnt, N_NODES);
    count_deg<<<(N_EDGES + 255) / 256, 256, 0, stream>>>(dst, cnt, N_EDGES);
    compute_dinv<<<(N_NODES + 255) / 256, 256, 0, stream>>>(cnt, dinv, N_NODES);
    scan_block_sums<<<nb, SCAN_B, 0, stream>>>(cnt, bsum, N_NODES);
    scan_bsums<<<1, 64, 0, stream>>>(bsum, nb, rowptr, N_NODES);
    scan_final<<<nb, SCAN_B, 0, stream>>>(cnt, bsum, rowptr, cursor, N_NODES);
    build_csr<<<(N_EDGES + 255) / 256, 256, 0, stream>>>(src, dst, dinv, cursor, colA, enorm, N_EDGES);

    const int agg_blocks = (N_NODES + 3) / 4;

    // ---- layer 1 ----
    linear64<<<2048, 256, 0, stream>>>(feature, W1, h, N_NODES);
    aggregate<<<agg_blocks, 256, 0, stream>>>(h, rowptr, colA, enorm, dinv, b1, out, N_NODES);

    // ---- layer 2 ----
    linear64<<<2048, 256, 0, stream>>>(out, W2, h, N_NODES);
    aggregate<<<agg_blocks, 256, 0, stream>>>(h, rowptr, colA, enorm, dinv, b2, out, N_NODES);
}

// Round 3
// 391.357 us; speedup vs baseline: 7.3503x; 1.2401x over previous
//
#include <hip/hip_runtime.h>

#define N_NODES 100000
#define N_EDGES 1600000
#define D 64
#define SCAN_B 256
#define SCAN_MAX 512   // must be >= ceil(N_NODES/SCAN_B) = 391

// ---------------- zero int buffer ----------------
__global__ void zero_int(int* __restrict__ p, int n) {
    int i = blockIdx.x * blockDim.x + threadIdx.x;
    if (i < n) p[i] = 0;
}

// ---------------- histogram of dst ----------------
__global__ void count_deg(const int* __restrict__ dst, int* __restrict__ cnt, int ne) {
    int i = blockIdx.x * blockDim.x + threadIdx.x;
    if (i < ne) atomicAdd(&cnt[dst[i]], 1);
}

// ---------------- dinv = rsqrt(cnt + 1)  (self-loop) ----------------
__global__ void compute_dinv(const int* __restrict__ cnt, float* __restrict__ dinv, int n) {
    int i = blockIdx.x * blockDim.x + threadIdx.x;
    if (i < n) dinv[i] = rsqrtf((float)cnt[i] + 1.0f);
}

// ---------------- per-block sums ----------------
__global__ void scan_block_sums(const int* __restrict__ cnt, int* __restrict__ bsum, int n) {
    __shared__ int s[SCAN_B];
    int i = blockIdx.x * SCAN_B + threadIdx.x;
    s[threadIdx.x] = (i < n) ? cnt[i] : 0;
    __syncthreads();
    for (int off = SCAN_B / 2; off > 0; off >>= 1) {
        if (threadIdx.x < off) s[threadIdx.x] += s[threadIdx.x + off];
        __syncthreads();
    }
    if (threadIdx.x == 0) bsum[blockIdx.x] = s[0];
}

// ---------------- one-block parallel exclusive scan of bsum ----------------
__global__ void scan_small(int* __restrict__ bsum, int nb, int* __restrict__ rowptr, int n) {
    __shared__ int s[SCAN_MAX];
    const int t = threadIdx.x;  // 512 threads
    int v = (t < nb) ? bsum[t] : 0;
    s[t] = v;
    __syncthreads();
    for (int off = 1; off < SCAN_MAX; off <<= 1) {
        int u = (t >= off) ? s[t - off] : 0;
        __syncthreads();
        s[t] += u;
        __syncthreads();
    }
    if (t < nb) bsum[t] = s[t] - v;              // exclusive
    if (t == SCAN_MAX - 1) rowptr[n] = s[t];     // total = N_EDGES
}

// ---------------- per-block scan + offset -> rowptr, cursor ----------------
__global__ void scan_final(const int* __restrict__ cnt, const int* __restrict__ bsum,
                           int* __restrict__ rowptr, int* __restrict__ cursor, int n) {
    __shared__ int s[SCAN_B];
    int i = blockIdx.x * SCAN_B + threadIdx.x;
    int v = (i < n) ? cnt[i] : 0;
    s[threadIdx.x] = v;
    __syncthreads();
    for (int off = 1; off < SCAN_B; off <<= 1) {
        int t = (threadIdx.x >= off) ? s[threadIdx.x - off] : 0;
        __syncthreads();
        s[threadIdx.x] += t;
        __syncthreads();
    }
    if (i < n) {
        int excl = s[threadIdx.x] - v + bsum[blockIdx.x];
        rowptr[i] = excl;
        cursor[i] = excl;
    }
}

// ---------------- bucket edges: col[pos]=src (no enorm — computed on the fly) ----------------
__global__ void build_csr(const int* __restrict__ src, const int* __restrict__ dst,
                          int* __restrict__ cursor, int* __restrict__ col, int ne) {
    int e = blockIdx.x * blockDim.x + threadIdx.x;
    if (e >= ne) return;
    int pos = atomicAdd(&cursor[dst[e]], 1);
    col[pos] = src[e];
}

// ---------------- fused GCN layer: out = relu((A_hat x) W + b) ----------------
// One wave per node. lane = feature index. W column held in 64 VGPRs.
// Cross-lane broadcast via v_readlane (VALU, no LDS).
__device__ __forceinline__ float rlane_f(float v, int l) {
    return __int_as_float(__builtin_amdgcn_readlane(__float_as_int(v), l));
}
__device__ __forceinline__ int rlane_i(int v, int l) {
    return __builtin_amdgcn_readlane(v, l);
}

__global__ __launch_bounds__(256) void gcn_layer(
        const float* __restrict__ x, const int* __restrict__ rowptr,
        const int* __restrict__ col, const float* __restrict__ dinv,
        const float* __restrict__ W, const float* __restrict__ bias,
        float* __restrict__ out, int n) {
    const int lane = threadIdx.x & 63;
    const int gwave = (blockIdx.x * blockDim.x + threadIdx.x) >> 6;
    const int nwaves = (gridDim.x * blockDim.x) >> 6;

    // W column for this lane: wcol[k] = W[k][lane]
    float wcol[64];
#pragma unroll
    for (int k = 0; k < 64; ++k) wcol[k] = W[k * 64 + lane];
    const float bv = bias[lane];

    for (int nd = gwave; nd < n; nd += nwaves) {
        const int beg = rowptr[nd];
        const int end = rowptr[nd + 1];
        const float dv = dinv[nd];

        float acc0 = 0.f, acc1 = 0.f, acc2 = 0.f, acc3 = 0.f;
        int j = beg;
        while (j < end) {
            const int chunk = min(end - j, 64);
            int s_l = 0;
            float w_l = 0.f;
            if (lane < chunk) {
                s_l = col[j + lane];      // coalesced
                w_l = dinv[s_l];          // small gather, L2-resident
            }
            int t = 0;
            for (; t + 3 < chunk; t += 4) {
                const int   s0 = rlane_i(s_l, t + 0), s1 = rlane_i(s_l, t + 1);
                const int   s2 = rlane_i(s_l, t + 2), s3 = rlane_i(s_l, t + 3);
                const float w0 = rlane_f(w_l, t + 0), w1 = rlane_f(w_l, t + 1);
                const float w2 = rlane_f(w_l, t + 2), w3 = rlane_f(w_l, t + 3);
                acc0 = fmaf(x[(size_t)s0 * D + lane], w0, acc0);
                acc1 = fmaf(x[(size_t)s1 * D + lane], w1, acc1);
                acc2 = fmaf(x[(size_t)s2 * D + lane], w2, acc2);
                acc3 = fmaf(x[(size_t)s3 * D + lane], w3, acc3);
            }
            for (; t < chunk; ++t) {
                const int   s0 = rlane_i(s_l, t);
                const float w0 = rlane_f(w_l, t);
                acc0 = fmaf(x[(size_t)s0 * D + lane], w0, acc0);
            }
            j += chunk;
        }
        // a = dv * sum + dv^2 * x[node]   (self-loop weight 1/deg)
        const float xn = x[(size_t)nd * D + lane];
        const float a = fmaf(dv, (acc0 + acc1) + (acc2 + acc3), dv * dv * xn);

        // GEMM row: g[lane] = sum_k a_k * W[k][lane] via readlane broadcast
        float g0 = 0.f, g1 = 0.f, g2 = 0.f, g3 = 0.f;
#pragma unroll
        for (int k = 0; k < 64; k += 4) {
            g0 = fmaf(rlane_f(a, k + 0), wcol[k + 0], g0);
            g1 = fmaf(rlane_f(a, k + 1), wcol[k + 1], g1);
            g2 = fmaf(rlane_f(a, k + 2), wcol[k + 2], g2);
            g3 = fmaf(rlane_f(a, k + 3), wcol[k + 3], g3);
        }
        out[(size_t)nd * D + lane] = fmaxf((g0 + g1) + (g2 + g3) + bv, 0.f);
    }
}

extern "C" void kernel_launch(void* const* d_in, const int* in_sizes, int n_in,
                              void* d_out, int out_size, void* d_ws, size_t ws_size,
                              hipStream_t stream) {
    const float* feature = (const float*)d_in[0];
    const int*   edges   = (const int*)d_in[1];   // [2, E] flat: src then dst
    const float* W1      = (const float*)d_in[2];
    const float* b1      = (const float*)d_in[3];
    const float* W2      = (const float*)d_in[4];
    const float* b2      = (const float*)d_in[5];
    float* out = (float*)d_out;

    const int* src = edges;
    const int* dst = edges + N_EDGES;

    // workspace layout
    char* w = (char*)d_ws;
    int*   cnt    = (int*)w;            w += sizeof(int) * (N_NODES);
    int*   rowptr = (int*)w;            w += sizeof(int) * (N_NODES + 1);
    int*   cursor = (int*)w;            w += sizeof(int) * (N_NODES);
    int*   bsum   = (int*)w;            w += sizeof(int) * SCAN_MAX;
    int*   colA   = (int*)w;            w += sizeof(int) * (N_EDGES);
    float* dinv   = (float*)w;          w += sizeof(float) * (N_NODES);
    float* y1     = (float*)w;          w += sizeof(float) * ((size_t)N_NODES * D);

    const int nb = (N_NODES + SCAN_B - 1) / SCAN_B;  // 391 <= SCAN_MAX

    // ---- CSR build (once, shared by both layers) ----
    zero_int<<<(N_NODES + 255) / 256, 256, 0, stream>>>(cnt, N_NODES);
    count_deg<<<(N_EDGES + 255) / 256, 256, 0, stream>>>(dst, cnt, N_EDGES);
    compute_dinv<<<(N_NODES + 255) / 256, 256, 0, stream>>>(cnt, dinv, N_NODES);
    scan_block_sums<<<nb, SCAN_B, 0, stream>>>(cnt, bsum, N_NODES);
    scan_small<<<1, SCAN_MAX, 0, stream>>>(bsum, nb, rowptr, N_NODES);
    scan_final<<<nb, SCAN_B, 0, stream>>>(cnt, bsum, rowptr, cursor, N_NODES);
    build_csr<<<(N_EDGES + 255) / 256, 256, 0, stream>>>(src, dst, cursor, colA, N_EDGES);

    // ---- fused layers: layer1 feature->y1, layer2 y1->out (no aliasing) ----
    gcn_layer<<<1024, 256, 0, stream>>>(feature, rowptr, colA, dinv, W1, b1, y1, N_NODES);
    gcn_layer<<<1024, 256, 0, stream>>>(y1, rowptr, colA, dinv, W2, b2, out, N_NODES);
}

// Round 4
// 302.035 us; speedup vs baseline: 9.5240x; 1.2957x over previous
//
#include <hip/hip_runtime.h>

#define N_NODES 100000
#define N_EDGES 1600000
#define D 64

#define NB 2048                 // buckets (power of 2)
#define BUCKET_W 49             // nodes per bucket: 2041 buckets used
#define NB_USED ((N_NODES + BUCKET_W - 1) / BUCKET_W)   // 2041
#define AB_BLOCKS 256           // blocks for pass A/B (must match for group ids)
#define CHUNK ((N_EDGES + AB_BLOCKS - 1) / AB_BLOCKS)   // 6250
#define CCAP 1536               // max edges per bucket (mean 784, sd 28 -> never hit)

// ---------------- zero int buffer ----------------
__global__ void zero_int(int* __restrict__ p, int n) {
    int i = blockIdx.x * blockDim.x + threadIdx.x;
    if (i < n) p[i] = 0;
}

// ---------------- pass A: histogram dst into (bucket, group) ----------------
__global__ __launch_bounds__(256) void bucket_count(const int* __restrict__ dst,
                                                    int* __restrict__ gcount) {
    __shared__ int h[NB];
    for (int i = threadIdx.x; i < NB; i += 256) h[i] = 0;
    __syncthreads();
    const int blk = blockIdx.x;
    const int g = blk & 7;
    const int beg = blk * CHUNK;
    const int end = min(beg + CHUNK, N_EDGES);
    for (int e = beg + threadIdx.x; e < end; e += 256)
        atomicAdd(&h[dst[e] / BUCKET_W], 1);
    __syncthreads();
    for (int i = threadIdx.x; i < NB; i += 256) {
        int v = h[i];
        if (v) atomicAdd(&gcount[i * 8 + g], v);
    }
}

// ---------------- scan of 16384 (bucket,group) counts -> subbase & cursor ----------------
__global__ __launch_bounds__(1024) void scan16k(const int* __restrict__ gcount,
                                                int* __restrict__ subbase,
                                                int* __restrict__ cursor,
                                                int* __restrict__ rowptr) {
    __shared__ int s[1024];
    const int t = threadIdx.x;
    int loc[16];
    int sum = 0;
#pragma unroll
    for (int i = 0; i < 16; ++i) { loc[i] = gcount[t * 16 + i]; sum += loc[i]; }
    s[t] = sum;
    __syncthreads();
    for (int off = 1; off < 1024; off <<= 1) {
        int u = (t >= off) ? s[t - off] : 0;
        __syncthreads();
        s[t] += u;
        __syncthreads();
    }
    int excl = s[t] - sum;
#pragma unroll
    for (int i = 0; i < 16; ++i) {
        int idx = t * 16 + i;
        subbase[idx] = excl;
        cursor[idx] = excl;
        excl += loc[i];
    }
    if (t == 1023) { subbase[16384] = excl; rowptr[N_NODES] = N_EDGES; }
}

// ---------------- pass B: scatter packed edges into (bucket,group) sub-regions ----------------
__global__ __launch_bounds__(256) void partition_edges(const int* __restrict__ src,
                                                       const int* __restrict__ dst,
                                                       int* __restrict__ cursor,
                                                       int* __restrict__ part) {
    const int blk = blockIdx.x;
    const int g = blk & 7;
    const int beg = blk * CHUNK;
    const int end = min(beg + CHUNK, N_EDGES);
    for (int e = beg + threadIdx.x; e < end; e += 256) {
        const int d = dst[e];
        const int s = src[e];
        const int b = d / BUCKET_W;
        const int local = d - b * BUCKET_W;
        const int pos = atomicAdd(&cursor[b * 8 + g], 1);
        part[pos] = (s << 6) | local;
    }
}

// ---------------- pass C: per-bucket counting sort -> col, rowptr, dinv ----------------
__global__ __launch_bounds__(256) void bucket_csr(const int* __restrict__ subbase,
                                                  const int* __restrict__ part,
                                                  int* __restrict__ col,
                                                  int* __restrict__ rowptr,
                                                  float* __restrict__ dinv) {
    __shared__ int ed[CCAP];
    __shared__ int hist[BUCKET_W];
    __shared__ int offs[BUCKET_W];
    __shared__ int lcur[BUCKET_W];
    const int b = blockIdx.x;
    const int base = subbase[b * 8];
    const int cnt = min(subbase[(b + 1) * 8] - base, CCAP);
    const int n0 = b * BUCKET_W;
    const int nn = min(N_NODES - n0, BUCKET_W);
    const int t = threadIdx.x;

    if (t < BUCKET_W) hist[t] = 0;
    for (int i = t; i < cnt; i += 256) ed[i] = part[base + i];
    __syncthreads();
    for (int i = t; i < cnt; i += 256) atomicAdd(&hist[ed[i] & 63], 1);
    __syncthreads();
    if (t == 0) {
        int a = 0;
        for (int i = 0; i < nn; ++i) { offs[i] = a; lcur[i] = a; a += hist[i]; }
    }
    __syncthreads();
    if (t < nn) {
        rowptr[n0 + t] = base + offs[t];
        dinv[n0 + t] = rsqrtf((float)hist[t] + 1.0f);
    }
    for (int i = t; i < cnt; i += 256) {
        const int p = ed[i];
        const int pos = atomicAdd(&lcur[p & 63], 1);
        col[base + pos] = p >> 6;   // writes land in a ~3KB window: no amplification
    }
}

// ---------------- fused GCN layer: out = relu((A_hat x) W + b) ----------------
__device__ __forceinline__ float rlane_f(float v, int l) {
    return __int_as_float(__builtin_amdgcn_readlane(__float_as_int(v), l));
}
__device__ __forceinline__ int rlane_i(int v, int l) {
    return __builtin_amdgcn_readlane(v, l);
}

__global__ __launch_bounds__(256) void gcn_layer(
        const float* __restrict__ x, const int* __restrict__ rowptr,
        const int* __restrict__ col, const float* __restrict__ dinv,
        const float* __restrict__ W, const float* __restrict__ bias,
        float* __restrict__ out, int n) {
    const int lane = threadIdx.x & 63;
    const int gwave = (blockIdx.x * blockDim.x + threadIdx.x) >> 6;
    const int nwaves = (gridDim.x * blockDim.x) >> 6;

    float wcol[64];
#pragma unroll
    for (int k = 0; k < 64; ++k) wcol[k] = W[k * 64 + lane];
    const float bv = bias[lane];

    for (int nd = gwave; nd < n; nd += nwaves) {
        const int beg = rowptr[nd];
        const int end = rowptr[nd + 1];
        const float dv = dinv[nd];

        float acc0 = 0.f, acc1 = 0.f, acc2 = 0.f, acc3 = 0.f;
        int j = beg;
        while (j < end) {
            const int chunk = min(end - j, 64);
            int s_l = 0;
            float w_l = 0.f;
            if (lane < chunk) {
                s_l = col[j + lane];      // coalesced
                w_l = dinv[s_l];          // small gather, L2-resident
            }
            int t = 0;
            for (; t + 3 < chunk; t += 4) {
                const int   s0 = rlane_i(s_l, t + 0), s1 = rlane_i(s_l, t + 1);
                const int   s2 = rlane_i(s_l, t + 2), s3 = rlane_i(s_l, t + 3);
                const float w0 = rlane_f(w_l, t + 0), w1 = rlane_f(w_l, t + 1);
                const float w2 = rlane_f(w_l, t + 2), w3 = rlane_f(w_l, t + 3);
                acc0 = fmaf(x[(size_t)s0 * D + lane], w0, acc0);
                acc1 = fmaf(x[(size_t)s1 * D + lane], w1, acc1);
                acc2 = fmaf(x[(size_t)s2 * D + lane], w2, acc2);
                acc3 = fmaf(x[(size_t)s3 * D + lane], w3, acc3);
            }
            for (; t < chunk; ++t) {
                const int   s0 = rlane_i(s_l, t);
                const float w0 = rlane_f(w_l, t);
                acc0 = fmaf(x[(size_t)s0 * D + lane], w0, acc0);
            }
            j += chunk;
        }
        const float xn = x[(size_t)nd * D + lane];
        const float a = fmaf(dv, (acc0 + acc1) + (acc2 + acc3), dv * dv * xn);

        float g0 = 0.f, g1 = 0.f, g2 = 0.f, g3 = 0.f;
#pragma unroll
        for (int k = 0; k < 64; k += 4) {
            g0 = fmaf(rlane_f(a, k + 0), wcol[k + 0], g0);
            g1 = fmaf(rlane_f(a, k + 1), wcol[k + 1], g1);
            g2 = fmaf(rlane_f(a, k + 2), wcol[k + 2], g2);
            g3 = fmaf(rlane_f(a, k + 3), wcol[k + 3], g3);
        }
        out[(size_t)nd * D + lane] = fmaxf((g0 + g1) + (g2 + g3) + bv, 0.f);
    }
}

extern "C" void kernel_launch(void* const* d_in, const int* in_sizes, int n_in,
                              void* d_out, int out_size, void* d_ws, size_t ws_size,
                              hipStream_t stream) {
    const float* feature = (const float*)d_in[0];
    const int*   edges   = (const int*)d_in[1];   // [2, E] flat: src then dst
    const float* W1      = (const float*)d_in[2];
    const float* b1      = (const float*)d_in[3];
    const float* W2      = (const float*)d_in[4];
    const float* b2      = (const float*)d_in[5];
    float* out = (float*)d_out;

    const int* src = edges;
    const int* dst = edges + N_EDGES;

    // workspace layout
    char* w = (char*)d_ws;
    int*   gcount  = (int*)w;   w += sizeof(int) * (NB * 8);          // 16384
    int*   subbase = (int*)w;   w += sizeof(int) * (NB * 8 + 1);      // 16385
    int*   cursor  = (int*)w;   w += sizeof(int) * (NB * 8);          // 16384
    int*   rowptr  = (int*)w;   w += sizeof(int) * (N_NODES + 1);
    float* dinv    = (float*)w; w += sizeof(float) * (N_NODES);
    int*   part    = (int*)w;   w += sizeof(int) * (N_EDGES);
    int*   colA    = (int*)w;   w += sizeof(int) * (N_EDGES);
    float* y1      = (float*)w; w += sizeof(float) * ((size_t)N_NODES * D);

    // ---- CSR build (bucketed two-level partition) ----
    zero_int<<<(NB * 8 + 255) / 256, 256, 0, stream>>>(gcount, NB * 8);
    bucket_count<<<AB_BLOCKS, 256, 0, stream>>>(dst, gcount);
    scan16k<<<1, 1024, 0, stream>>>(gcount, subbase, cursor, rowptr);
    partition_edges<<<AB_BLOCKS, 256, 0, stream>>>(src, dst, cursor, part);
    bucket_csr<<<NB_USED, 256, 0, stream>>>(subbase, part, colA, rowptr, dinv);

    // ---- fused layers: layer1 feature->y1, layer2 y1->out ----
    gcn_layer<<<2048, 256, 0, stream>>>(feature, rowptr, colA, dinv, W1, b1, y1, N_NODES);
    gcn_layer<<<2048, 256, 0, stream>>>(y1, rowptr, colA, dinv, W2, b2, out, N_NODES);
}